// Round 2
// baseline (179.588 us; speedup 1.0000x reference)
//
#include <hip/hip_runtime.h>
#include <math.h>

#define TAU_CONST 1.0f
#define BLOCK 256
#define RPT 4                        // rows per thread
#define RPB (BLOCK * RPT)            // 1024 rows per block
#define F4PB (RPB * 5 / 4)           // 1280 float4 per input per block (20 KB)

__device__ __forceinline__ float fast_rcp(float x) { return __builtin_amdgcn_rcpf(x); }

__device__ __forceinline__ float kld_row(const float* p, const float* t) {
    float pw = fminf(fmaxf(p[2], 1e-7f), 1e7f), ph = fminf(fmaxf(p[3], 1e-7f), 1e7f);
    float tw = fminf(fmaxf(t[2], 1e-7f), 1e7f), th = fminf(fmaxf(t[3], 1e-7f), 1e7f);
    float ap = 0.25f * pw * pw, bp = 0.25f * ph * ph;
    float at = 0.25f * tw * tw, bt = 0.25f * th * th;
    float sp_, cp_; __sincosf(p[4], &sp_, &cp_);
    float st_, ct_; __sincosf(t[4], &st_, &ct_);
    float p00 = ap * cp_ * cp_ + bp * sp_ * sp_;
    float p11 = ap * sp_ * sp_ + bp * cp_ * cp_;
    float p01 = (ap - bp) * sp_ * cp_;
    float t00 = at * ct_ * ct_ + bt * st_ * st_;
    float t11 = at * st_ * st_ + bt * ct_ * ct_;
    float t01 = (at - bt) * st_ * ct_;
    float dp = p00 * p11 - p01 * p01;
    float dt = t00 * t11 - t01 * t01;
    float dx = p[0] - t[0], dy = p[1] - t[1];
    float inv_dt = fast_rcp(dt);
    float term1 = (dx * dx * t11 - 2.0f * dx * dy * t01 + dy * dy * t00) * inv_dt;
    float tr    = (t11 * p00 + t00 * p11 - 2.0f * t01 * p01) * inv_dt;
    float term2 = tr + (__logf(dt) - __logf(dp));
    float dis = term1 + term2 - 2.0f;
    float kl = fmaxf(dis, 1e-6f);
    return 1.0f - fast_rcp(TAU_CONST + __logf(1.0f + kl));
}

// Block stages RPB rows of both inputs into LDS with perfectly coalesced
// float4 loads (lane-contiguous), then each thread reads its 4 rows
// (5 x ds_read_b128, bank-uniform since 5*lane+k covers all groups mod 8).
__global__ void __launch_bounds__(BLOCK) gdloss_lds_kernel(const float4* __restrict__ pred4,
                                                           const float4* __restrict__ targ4,
                                                           float4* __restrict__ out4,
                                                           int nf4_in, int n4_out) {
    __shared__ float4 sP[F4PB];
    __shared__ float4 sT[F4PB];
    const int tid = threadIdx.x;
    const int base4 = blockIdx.x * F4PB;
#pragma unroll
    for (int k = 0; k < 5; ++k) {
        int g = base4 + k * BLOCK + tid;
        float4 v, u;
        if (g < nf4_in) { v = pred4[g]; u = targ4[g]; }
        else            { v = float4{0, 0, 0, 0}; u = float4{0, 0, 0, 0}; }
        sP[k * BLOCK + tid] = v;
        sT[k * BLOCK + tid] = u;
    }
    __syncthreads();
    const float4* pRow = (const float4*)((const float*)sP + 20 * tid);  // 80B-aligned
    const float4* tRow = (const float4*)((const float*)sT + 20 * tid);
    float4 lp[5], lt[5];
#pragma unroll
    for (int k = 0; k < 5; ++k) { lp[k] = pRow[k]; lt[k] = tRow[k]; }
    const float* P = (const float*)lp;
    const float* T = (const float*)lt;
    float4 o;
    o.x = kld_row(P + 0,  T + 0);
    o.y = kld_row(P + 5,  T + 5);
    o.z = kld_row(P + 10, T + 10);
    o.w = kld_row(P + 15, T + 15);
    int o4 = blockIdx.x * BLOCK + tid;
    if (o4 < n4_out) out4[o4] = o;
}

// Scalar tail for n % 4 rows (not hit at N=4M; kept for generality).
__global__ void gdloss_tail_kernel(const float* __restrict__ pred,
                                   const float* __restrict__ target,
                                   float* __restrict__ out, int start, int n) {
    int i = start + blockIdx.x * blockDim.x + threadIdx.x;
    if (i >= n) return;
    float p[5], t[5];
#pragma unroll
    for (int k = 0; k < 5; ++k) { p[k] = pred[5 * i + k]; t[k] = target[5 * i + k]; }
    out[i] = kld_row(p, t);
}

extern "C" void kernel_launch(void* const* d_in, const int* in_sizes, int n_in,
                              void* d_out, int out_size, void* d_ws, size_t ws_size,
                              hipStream_t stream) {
    const float* pred   = (const float*)d_in[0];
    const float* target = (const float*)d_in[1];
    float* out = (float*)d_out;
    const int n = in_sizes[0] / 5;          // rows
    const int n4 = n / 4;                   // full float4 output groups
    const int nf4_in = (n * 5) / 4;         // full float4s per input
    if (n4 > 0) {
        int blocks = (n4 + BLOCK - 1) / BLOCK;
        gdloss_lds_kernel<<<blocks, BLOCK, 0, stream>>>((const float4*)pred,
                                                        (const float4*)target,
                                                        (float4*)out, nf4_in, n4);
    }
    if (n - n4 * 4 > 0) {
        gdloss_tail_kernel<<<1, 64, 0, stream>>>(pred, target, out, n4 * 4, n);
    }
}